// Round 11
// baseline (103.284 us; speedup 1.0000x reference)
//
#include <hip/hip_runtime.h>
#include <math.h>

// B=4096 rows, D=128 fp32.
// v = x*(-sp/denp + 0.5*sn/denn) + (Wp@yp)/denp - 0.5*(Wn@yn)/denn
// s ~ 1e-26 << EPS=1e-8; only pairs with d2 < ~146 matter (threshold 2e-20).
// Round 11: best-of-all-rounds recombination.
//  - prep_k (r5): norms + swizzled bf16 matrix build in ws + acc zeroing.
//  - phase_a (r5 staging): global_load_lds from the L2-warm bf16 matrices
//    (r8/r10 read cold fp32 originals + inline cvt -> pinned at 41us; r5's
//    warm-matrix staging ran <41us), K=128, BK=64, [row][64] chunk-XOR LDS
//    layout (0 conflicts measured r3-r5; r9/r10's [row][32] = 16-bank row
//    stride reintroduced 1M conflict cycles).
//  - flush (r8): exact fp32 dot per survivor pair, unscaled w*y[j] acc
//    atomics; finalize applies exact 1/den. No scatter kernel, no global
//    counters (r2-r4: shared-address atomic chains cost 40-120us).

#define EPSV 1e-8f
#define CUTOFF_F 162.0f
#define LCAP 512

typedef unsigned int uint;
typedef unsigned short ushort;
typedef __attribute__((ext_vector_type(8))) short bf16x8;
typedef __attribute__((ext_vector_type(4))) float f32x4;

// ws float layout: 0 sp[4096]; 4096 sn[4096]; 8192 xsq[4096];
//   12288 ysqp[4096]; 16384 ysqn[4096];
//   20480 accp[524288]; 544768 accn[524288]  (ends float 1069056 = 4.28 MB)
// bytes: 4718592 XA bf16[4096*128]; +1MiB YPB; +2MiB YNB (end 7864320)
#define ACC_IDX 20480u
#define XA_BYTE 4718592u
#define MAT_BYTES 1048576u
#define WS_NEED 7864320u

static __device__ __forceinline__ ushort bf16_rne(float v) {
    uint u = __float_as_uint(v);
    uint r = (u + 0x7FFFu + ((u >> 16) & 1u)) >> 16;
    return (ushort)r;
}

typedef const __attribute__((address_space(1))) uint guint;
typedef __attribute__((address_space(3))) uint luint;
static __device__ __forceinline__ void lds_load16(const void* g, void* l) {
    __builtin_amdgcn_global_load_lds((guint*)g, (luint*)l, 16, 0, 0);
}

// norms + swizzled bf16 matrix build + zeroing. One wave per row.
// Swizzle: within each 64-elem K-group, physical chunk c (8 bf16) holds
// logical chunk c ^ (row&7).
__global__ __launch_bounds__(256) void prep_k(
    const float* __restrict__ x, const float* __restrict__ yp,
    const float* __restrict__ yn, float* __restrict__ ws,
    unsigned char* __restrict__ wsb, int build)
{
    __shared__ ushort hi_s[4][128];
    const int t = threadIdx.x, wv = t >> 6, lane = t & 63;
    const int rid = blockIdx.x * 4 + wv;          // 0..12287
    const int seg = rid >> 12;                    // 0:x 1:yp 2:yn
    const int row = rid & 4095;
    const float* src = (seg == 0) ? x : (seg == 1) ? yp : yn;

    float2 v = ((const float2*)(src + (size_t)row * 128))[lane];
    float ss = v.x * v.x + v.y * v.y;
    #pragma unroll
    for (int off = 32; off > 0; off >>= 1) ss += __shfl_down(ss, off);
    if (lane == 0) ws[8192 + seg * 4096 + row] = ss;

    if (build) {
        hi_s[wv][2 * lane]     = bf16_rne(v.x);
        hi_s[wv][2 * lane + 1] = bf16_rne(v.y);
        __syncthreads();
        const int K = 2 * lane;
        const int g = K >> 6, c = (K >> 3) & 7, off = K & 7;
        const int Klog = (g << 6) + ((c ^ (row & 7)) << 3) + off;
        uint* dst = (uint*)(wsb + XA_BYTE + (size_t)seg * MAT_BYTES) + (size_t)row * 64;
        dst[lane] = (uint)hi_s[wv][Klog] | ((uint)hi_s[wv][Klog + 1] << 16);
    }

    // zero sp/sn (8192 floats) + accp/accn (1048576 floats at ACC_IDX)
    const uint gid = blockIdx.x * 256u + (uint)t; // 0..786431
    for (uint u = gid; u < 1056768u; u += 786432u) {
        const uint idx = (u < 8192u) ? u : (u + 12288u);
        ws[idx] = 0.0f;
    }
}

// MFMA filter GEMM, one field per block-z. 128x128 tile, 4 waves x 64x64.
// global_load_lds staging from the warm bf16 matrices; K=128 in 2 rounds.
__global__ __launch_bounds__(256) void phase_a_mfma(
    const float* __restrict__ x, const float* __restrict__ yp,
    const float* __restrict__ yn,
    const unsigned char* __restrict__ wsb, float* __restrict__ wsf)
{
    const int f = blockIdx.z;
    const ushort* __restrict__ XA = (const ushort*)(wsb + XA_BYTE);
    const ushort* __restrict__ YB = (const ushort*)(wsb + XA_BYTE + (f ? 2u : 1u) * MAT_BYTES);
    const float* __restrict__ Yg  = f ? yn : yp;

    __shared__ ushort As[128 * 64];   // 16 KB per K-half, [8-row grp][64]
    __shared__ ushort Bs[128 * 64];
    __shared__ uint pbuf[LCAP];       // 2 KB pair keys
    __shared__ uint pcnt;

    const int t = threadIdx.x;
    const int lane = t & 63, wv = t >> 6;
    const int wr = wv >> 1, wc = wv & 1;          // 64x64 per wave
    const int i0 = blockIdx.y * 128, j0 = blockIdx.x * 128;
    const int m = lane & 15, qd = lane >> 4;
    const int srow = lane >> 3;                   // 0..7
    const int scol = lane & 7;                    // physical chunk 0..7

    if (t == 0) pcnt = 0;

    f32x4 acc[4][4];
    #pragma unroll
    for (int a = 0; a < 4; ++a)
        #pragma unroll
        for (int bb = 0; bb < 4; ++bb) acc[a][bb] = (f32x4)0.0f;

    for (int k0 = 0; k0 < 128; k0 += 64) {
        #pragma unroll
        for (int q = 0; q < 4; ++q) {
            const int grp = 4 * wv + q;           // 0..15 (8 rows each)
            const int r = grp * 8 + srow;
            lds_load16(XA + (size_t)(i0 + r) * 128 + k0 + scol * 8, &As[grp * 512]);
            lds_load16(YB + (size_t)(j0 + r) * 128 + k0 + scol * 8, &Bs[grp * 512]);
        }
        __syncthreads();
        #pragma unroll
        for (int ks = 0; ks < 2; ++ks) {
            const int ca = (4 * ks + qd) ^ (m & 7);   // ra&7 == m&7
            bf16x8 av[4], bv[4];
            #pragma unroll
            for (int ff = 0; ff < 4; ++ff) {
                const int ra = 64 * wr + 16 * ff + m;
                av[ff] = *(const bf16x8*)&As[ra * 64 + ca * 8];
                const int rb = 64 * wc + 16 * ff + m;
                bv[ff] = *(const bf16x8*)&Bs[rb * 64 + ca * 8];
            }
            #pragma unroll
            for (int fi = 0; fi < 4; ++fi)
                #pragma unroll
                for (int fj = 0; fj < 4; ++fj)
                    acc[fi][fj] = __builtin_amdgcn_mfma_f32_16x16x32_bf16(
                        av[fi], bv[fj], acc[fi][fj], 0, 0, 0);
        }
        __syncthreads();
    }

    // epilogue: approximate d2 filter (C layout: col=lane&15, row=qd*4+rg)
    const float* __restrict__ xsq = wsf + 8192;
    const float* __restrict__ ysq = wsf + 12288 + f * 4096;
    float xq[4][4], yq[4];
    #pragma unroll
    for (int fi = 0; fi < 4; ++fi)
        #pragma unroll
        for (int rg = 0; rg < 4; ++rg)
            xq[fi][rg] = xsq[i0 + 64 * wr + 16 * fi + 4 * qd + rg];
    #pragma unroll
    for (int fj = 0; fj < 4; ++fj)
        yq[fj] = ysq[j0 + 64 * wc + 16 * fj + m];

    #pragma unroll
    for (int fi = 0; fi < 4; ++fi) {
        #pragma unroll
        for (int fj = 0; fj < 4; ++fj) {
            #pragma unroll
            for (int rg = 0; rg < 4; ++rg) {
                const int i = i0 + 64 * wr + 16 * fi + 4 * qd + rg;
                const int j = j0 + 64 * wc + 16 * fj + m;
                float d2a = xq[fi][rg] + yq[fj] - 2.0f * acc[fi][fj][rg];
                if (d2a < CUTOFF_F && i != j) {
                    uint li = atomicAdd(&pcnt, 1u);   // LDS atomic
                    if (li < LCAP)
                        pbuf[li] = (uint)i | ((uint)j << 12);
                }
            }
        }
    }
    __syncthreads();

    // flush: one wave per pair, exact fp32 dot -> w; unscaled acc atomics
    float* __restrict__ S    = wsf + (f ? 4096 : 0);
    float* __restrict__ accF = wsf + ACC_IDX + (size_t)f * 524288u;
    uint n = pcnt; if (n > LCAP) n = LCAP;
    for (uint p = wv; p < n; p += 4) {
        const uint pk = pbuf[p];
        const uint i = pk & 0xFFFu, j = (pk >> 12) & 0xFFFu;
        float2 xa = ((const float2*)(x + (size_t)i * 128))[lane];
        float2 yb = ((const float2*)(Yg + (size_t)j * 128))[lane];
        float d = xa.x * yb.x + xa.y * yb.y;
        #pragma unroll
        for (int off = 32; off > 0; off >>= 1) d += __shfl_xor(d, off);
        const float d2 = fmaxf(xsq[i] + ysq[j] - 2.0f * d, 0.0f);
        const float w = __expf(-0.5f * d2);
        if (lane == 0) atomicAdd(&S[i], w);           // spread addresses
        float* __restrict__ accT = accF + (size_t)i * 128u;
        atomicAdd(&accT[2 * lane],     w * yb.x);
        atomicAdd(&accT[2 * lane + 1], w * yb.y);
    }
}

// fp32 fallback (only if ws too small — not expected): dense path into the
// same S/acc layout.
__global__ __launch_bounds__(256) void phase_a_f32(
    const float* __restrict__ x, const float* __restrict__ yp,
    const float* __restrict__ yn, float* __restrict__ ws)
{
    const int f = blockIdx.z;
    const float* __restrict__ Y   = f ? yn : yp;
    const float* __restrict__ xsq = ws + 8192;
    const float* __restrict__ ysq = ws + (f ? 16384 : 12288);
    float* __restrict__ S         = ws + (f ? 4096 : 0);
    float* __restrict__ accT      = ws + ACC_IDX + (size_t)f * 524288u;

    __shared__ float xs[32][128 + 4];
    __shared__ float ys[32][128 + 4];

    const int t  = threadIdx.x;
    const int tx = t & 15, ty = t >> 4;
    const int i0 = blockIdx.y * 128, j0 = blockIdx.x * 128;

    float acc[8][8];
    #pragma unroll
    for (int a = 0; a < 8; ++a)
        #pragma unroll
        for (int bb = 0; bb < 8; ++bb) acc[a][bb] = 0.f;

    const int ldr = t >> 1;
    const int ldk = (t & 1) * 16;

    for (int k0 = 0; k0 < 128; k0 += 32) {
        #pragma unroll
        for (int q = 0; q < 4; ++q) {
            float4 vx = *(const float4*)&x[(size_t)(i0 + ldr) * 128 + k0 + ldk + 4 * q];
            float4 vy = *(const float4*)&Y[(size_t)(j0 + ldr) * 128 + k0 + ldk + 4 * q];
            const int kb = ldk + 4 * q;
            xs[kb + 0][ldr] = vx.x; xs[kb + 1][ldr] = vx.y;
            xs[kb + 2][ldr] = vx.z; xs[kb + 3][ldr] = vx.w;
            ys[kb + 0][ldr] = vy.x; ys[kb + 1][ldr] = vy.y;
            ys[kb + 2][ldr] = vy.z; ys[kb + 3][ldr] = vy.w;
        }
        __syncthreads();
        #pragma unroll 4
        for (int kk = 0; kk < 32; ++kk) {
            float4 a0 = *(const float4*)&xs[kk][8 * ty];
            float4 a1 = *(const float4*)&xs[kk][8 * ty + 4];
            float4 b0 = *(const float4*)&ys[kk][8 * tx];
            float4 b1 = *(const float4*)&ys[kk][8 * tx + 4];
            float av[8] = {a0.x, a0.y, a0.z, a0.w, a1.x, a1.y, a1.z, a1.w};
            float bv[8] = {b0.x, b0.y, b0.z, b0.w, b1.x, b1.y, b1.z, b1.w};
            #pragma unroll
            for (int di = 0; di < 8; ++di)
                #pragma unroll
                for (int dj = 0; dj < 8; ++dj)
                    acc[di][dj] = fmaf(av[di], bv[dj], acc[di][dj]);
        }
        __syncthreads();
    }

    float xqv[8], yqv[8], srow[8];
    #pragma unroll
    for (int di = 0; di < 8; ++di) { xqv[di] = xsq[i0 + 8 * ty + di]; srow[di] = 0.f; }
    #pragma unroll
    for (int dj = 0; dj < 8; ++dj) yqv[dj] = ysq[j0 + 8 * tx + dj];

    #pragma unroll
    for (int di = 0; di < 8; ++di) {
        const int i = i0 + 8 * ty + di;
        #pragma unroll
        for (int dj = 0; dj < 8; ++dj) {
            const int j = j0 + 8 * tx + dj;
            float d2 = fmaxf(xqv[di] + yqv[dj] - 2.0f * acc[di][dj], 0.0f);
            if (i != j) {
                float w = __expf(-0.5f * d2);
                srow[di] += w;
                if (d2 < CUTOFF_F) {
                    const float* Yrow = Y + (size_t)j * 128;
                    for (int k = 0; k < 128; ++k)
                        atomicAdd(&accT[(size_t)i * 128 + k], w * Yrow[k]);
                }
            }
        }
    }
    #pragma unroll
    for (int di = 0; di < 8; ++di) {
        float v = srow[di];
        #pragma unroll
        for (int off = 8; off > 0; off >>= 1) v += __shfl_down(v, off, 16);
        if (tx == 0) atomicAdd(&S[i0 + 8 * ty + di], v);
    }
}

__global__ __launch_bounds__(256) void finalize_k(
    const float* __restrict__ x, const float* __restrict__ ws,
    float* __restrict__ out)
{
    const uint gid = blockIdx.x * 256u + threadIdx.x;  // 0..524287
    const uint i = gid >> 7;
    const float spv = ws[i], snv = ws[4096 + i];
    const float denp = fmaxf(spv, EPSV), denn = fmaxf(snv, EPSV);
    const float c = 0.5f * snv / denn - spv / denp;
    out[gid] = x[gid] * c
             + ws[ACC_IDX + gid] / denp
             - 0.5f * ws[ACC_IDX + 524288u + gid] / denn;
}

extern "C" void kernel_launch(void* const* d_in, const int* in_sizes, int n_in,
                              void* d_out, int out_size, void* d_ws, size_t ws_size,
                              hipStream_t stream)
{
    const float* x  = (const float*)d_in[0];
    const float* yp = (const float*)d_in[1];
    const float* yn = (const float*)d_in[2];
    float* out = (float*)d_out;
    float* ws  = (float*)d_ws;
    unsigned char* wsb = (unsigned char*)d_ws;

    const bool use_mfma = (ws_size >= WS_NEED);

    prep_k<<<3072, 256, 0, stream>>>(x, yp, yn, ws, wsb, use_mfma ? 1 : 0);
    dim3 ga(32, 32, 2);
    if (use_mfma) {
        phase_a_mfma<<<ga, 256, 0, stream>>>(x, yp, yn, wsb, ws);
    } else {
        phase_a_f32<<<ga, 256, 0, stream>>>(x, yp, yn, ws);
    }
    finalize_k<<<2048, 256, 0, stream>>>(x, ws, out);
}

// Round 12
// 101.603 us; speedup vs baseline: 1.0165x; 1.0165x over previous
//
#include <hip/hip_runtime.h>
#include <math.h>

// B=4096 rows, D=128 fp32.
// v = x*(-sp/denp + 0.5*sn/denn) + (Wp@yp)/denp - 0.5*(Wn@yn)/denn
// s ~ 1e-26 << EPS=1e-8; only pairs with d2 < ~146 matter (threshold 2e-20).
// Round 12: restore r8 verbatim — the empirical argmin (100.9us). r9-r11
// established: phase_a is pinned at ~41us (= the harness's 268MB 0xAA ws
// poison-fill duration) across warm-matrix staging, cold-fp32 inline cvt,
// register-direct, 2-8 blocks/CU, 0 vs 1M LDS conflicts — consistent with a
// post-fill dirty-line drain shadow throttling all memory traffic. Lightest
// prep + inline-cvt phase_a + fused flush/finalize is the best total.

#define EPSV 1e-8f
#define CUTOFF_F 162.0f
#define LCAP 512

typedef unsigned int uint;
typedef unsigned short ushort;
typedef __attribute__((ext_vector_type(8))) short bf16x8;
typedef __attribute__((ext_vector_type(4))) float f32x4;

// ws float layout: 0 sp[4096]; 4096 sn[4096]; 8192 xsq[4096];
//   12288 ysqp[4096]; 16384 ysqn[4096];
//   20480 accp[524288]; 544768 accn[524288]  (ends float 1069056 = 4.1 MiB)
#define ACC_IDX 20480u
#define WS_NEED 4276224u

static __device__ __forceinline__ ushort bf16_rne(float v) {
    uint u = __float_as_uint(v);
    uint r = (u + 0x7FFFu + ((u >> 16) & 1u)) >> 16;
    return (ushort)r;
}

// norms + zero sp/sn/accp/accn. One wave per row for norms.
__global__ __launch_bounds__(256) void prep_lite(
    const float* __restrict__ x, const float* __restrict__ yp,
    const float* __restrict__ yn, float* __restrict__ ws)
{
    const int t = threadIdx.x, wv = t >> 6, lane = t & 63;
    const int rid = blockIdx.x * 4 + wv;          // 0..12287
    const int seg = rid >> 12;                    // 0:x 1:yp 2:yn
    const int row = rid & 4095;
    const float* src = (seg == 0) ? x : (seg == 1) ? yp : yn;

    float2 v = ((const float2*)(src + (size_t)row * 128))[lane];
    float ss = v.x * v.x + v.y * v.y;
    #pragma unroll
    for (int off = 32; off > 0; off >>= 1) ss += __shfl_down(ss, off);
    if (lane == 0) ws[8192 + seg * 4096 + row] = ss;

    const uint gid = blockIdx.x * 256u + (uint)t; // 0..786431
    if (gid < 8192u) ws[gid] = 0.0f;              // sp, sn
    if (gid < 262144u)                            // acc: 1048576 floats as float4
        ((f32x4*)(ws + ACC_IDX))[gid] = (f32x4)0.0f;
}

// MFMA filter GEMM, one field per block-z. 128x128 tile, 4 waves x 64x64,
// BK=64 two-round K-loop. LDS layout [row][64] with chunk c at physical
// c^(row&7): ds_write_b128 staging and ds_read_b128 fragment reads both
// bank-uniform (0 conflicts measured r3-r5, r8).
__global__ __launch_bounds__(256, 4) void phase_a_mfma(
    const float* __restrict__ x, const float* __restrict__ yp,
    const float* __restrict__ yn, float* __restrict__ wsf)
{
    const int f = blockIdx.z;
    const float* __restrict__ Yg = f ? yn : yp;

    __shared__ ushort As[128 * 64];   // 16 KB per half-K
    __shared__ ushort Bs[128 * 64];
    __shared__ uint pbuf[LCAP];       // 2 KB pair keys
    __shared__ uint pcnt;

    const int t = threadIdx.x;
    const int lane = t & 63, wv = t >> 6;
    const int wr = wv >> 1, wc = wv & 1;          // 64x64 per wave
    const int i0 = blockIdx.y * 128, j0 = blockIdx.x * 128;
    const int m = lane & 15, qd = lane >> 4;

    if (t == 0) pcnt = 0;

    f32x4 acc[4][4];
    #pragma unroll
    for (int a = 0; a < 4; ++a)
        #pragma unroll
        for (int bb = 0; bb < 4; ++bb) acc[a][bb] = (f32x4)0.0f;

    for (int kh = 0; kh < 2; ++kh) {
        // stage: thread t, q in 0..3 -> write w = t + 256q: row r=w>>3,
        // chunk c=w&7 -> phys chunk c^(r&7). 8 floats -> 8 bf16 -> b128.
        #pragma unroll
        for (int q = 0; q < 4; ++q) {
            const int w = t + 256 * q;
            const int r = w >> 3, c = w & 7;
            const int pc = c ^ (r & 7);
            const float* ax = x + (size_t)(i0 + r) * 128 + kh * 64 + c * 8;
            const float* by = Yg + (size_t)(j0 + r) * 128 + kh * 64 + c * 8;
            float4 a0 = *(const float4*)ax, a1 = *(const float4*)(ax + 4);
            float4 b0 = *(const float4*)by, b1 = *(const float4*)(by + 4);
            union { ushort u[8]; bf16x8 v; } pa, pb;
            pa.u[0] = bf16_rne(a0.x); pa.u[1] = bf16_rne(a0.y);
            pa.u[2] = bf16_rne(a0.z); pa.u[3] = bf16_rne(a0.w);
            pa.u[4] = bf16_rne(a1.x); pa.u[5] = bf16_rne(a1.y);
            pa.u[6] = bf16_rne(a1.z); pa.u[7] = bf16_rne(a1.w);
            pb.u[0] = bf16_rne(b0.x); pb.u[1] = bf16_rne(b0.y);
            pb.u[2] = bf16_rne(b0.z); pb.u[3] = bf16_rne(b0.w);
            pb.u[4] = bf16_rne(b1.x); pb.u[5] = bf16_rne(b1.y);
            pb.u[6] = bf16_rne(b1.z); pb.u[7] = bf16_rne(b1.w);
            *(bf16x8*)&As[r * 64 + pc * 8] = pa.v;
            *(bf16x8*)&Bs[r * 64 + pc * 8] = pb.v;
        }
        __syncthreads();
        #pragma unroll
        for (int s = 0; s < 2; ++s) {
            const int phys = (4 * s + qd) ^ (m & 7);
            bf16x8 av[4], bv[4];
            #pragma unroll
            for (int ff = 0; ff < 4; ++ff) {
                const int ra = 64 * wr + 16 * ff + m;   // ra&7 == m&7
                av[ff] = *(const bf16x8*)&As[ra * 64 + phys * 8];
                const int rb = 64 * wc + 16 * ff + m;
                bv[ff] = *(const bf16x8*)&Bs[rb * 64 + phys * 8];
            }
            #pragma unroll
            for (int fi = 0; fi < 4; ++fi)
                #pragma unroll
                for (int fj = 0; fj < 4; ++fj)
                    acc[fi][fj] = __builtin_amdgcn_mfma_f32_16x16x32_bf16(
                        av[fi], bv[fj], acc[fi][fj], 0, 0, 0);
        }
        __syncthreads();
    }

    // epilogue: approximate d2 filter (C layout: col=lane&15, row=qd*4+rg)
    const float* __restrict__ xsq = wsf + 8192;
    const float* __restrict__ ysq = wsf + 12288 + f * 4096;
    float xq[4][4], yq[4];
    #pragma unroll
    for (int fi = 0; fi < 4; ++fi)
        #pragma unroll
        for (int rg = 0; rg < 4; ++rg)
            xq[fi][rg] = xsq[i0 + 64 * wr + 16 * fi + 4 * qd + rg];
    #pragma unroll
    for (int fj = 0; fj < 4; ++fj)
        yq[fj] = ysq[j0 + 64 * wc + 16 * fj + m];

    #pragma unroll
    for (int fi = 0; fi < 4; ++fi) {
        #pragma unroll
        for (int fj = 0; fj < 4; ++fj) {
            #pragma unroll
            for (int rg = 0; rg < 4; ++rg) {
                const int i = i0 + 64 * wr + 16 * fi + 4 * qd + rg;
                const int j = j0 + 64 * wc + 16 * fj + m;
                float d2a = xq[fi][rg] + yq[fj] - 2.0f * acc[fi][fj][rg];
                if (d2a < CUTOFF_F && i != j) {
                    uint li = atomicAdd(&pcnt, 1u);   // LDS atomic
                    if (li < LCAP)
                        pbuf[li] = (uint)i | ((uint)j << 12);
                }
            }
        }
    }
    __syncthreads();

    // flush: one wave per pair, exact fp32 dot -> w; unscaled acc atomics
    float* __restrict__ S    = wsf + (f ? 4096 : 0);
    float* __restrict__ accF = wsf + ACC_IDX + (size_t)f * 524288u;
    uint n = pcnt; if (n > LCAP) n = LCAP;
    for (uint p = wv; p < n; p += 4) {
        const uint pk = pbuf[p];
        const uint i = pk & 0xFFFu, j = (pk >> 12) & 0xFFFu;
        float2 xa = ((const float2*)(x + (size_t)i * 128))[lane];
        float2 yb = ((const float2*)(Yg + (size_t)j * 128))[lane];
        float d = xa.x * yb.x + xa.y * yb.y;
        #pragma unroll
        for (int off = 32; off > 0; off >>= 1) d += __shfl_xor(d, off);
        const float d2 = fmaxf(xsq[i] + ysq[j] - 2.0f * d, 0.0f);
        const float w = __expf(-0.5f * d2);
        if (lane == 0) atomicAdd(&S[i], w);           // spread addresses
        float* __restrict__ accT = accF + (size_t)i * 128u;
        atomicAdd(&accT[2 * lane],     w * yb.x);
        atomicAdd(&accT[2 * lane + 1], w * yb.y);
    }
}

// fp32 fallback (only if ws too small — not expected): dense path into the
// same S/acc layout.
__global__ __launch_bounds__(256) void phase_a_f32(
    const float* __restrict__ x, const float* __restrict__ yp,
    const float* __restrict__ yn, float* __restrict__ ws)
{
    const int f = blockIdx.z;
    const float* __restrict__ Y   = f ? yn : yp;
    const float* __restrict__ xsq = ws + 8192;
    const float* __restrict__ ysq = ws + (f ? 16384 : 12288);
    float* __restrict__ S         = ws + (f ? 4096 : 0);
    float* __restrict__ accT      = ws + ACC_IDX + (size_t)f * 524288u;

    __shared__ float xs[32][128 + 4];
    __shared__ float ys[32][128 + 4];

    const int t  = threadIdx.x;
    const int tx = t & 15, ty = t >> 4;
    const int i0 = blockIdx.y * 128, j0 = blockIdx.x * 128;

    float acc[8][8];
    #pragma unroll
    for (int a = 0; a < 8; ++a)
        #pragma unroll
        for (int bb = 0; bb < 8; ++bb) acc[a][bb] = 0.f;

    const int ldr = t >> 1;
    const int ldk = (t & 1) * 16;

    for (int k0 = 0; k0 < 128; k0 += 32) {
        #pragma unroll
        for (int q = 0; q < 4; ++q) {
            float4 vx = *(const float4*)&x[(size_t)(i0 + ldr) * 128 + k0 + ldk + 4 * q];
            float4 vy = *(const float4*)&Y[(size_t)(j0 + ldr) * 128 + k0 + ldk + 4 * q];
            const int kb = ldk + 4 * q;
            xs[kb + 0][ldr] = vx.x; xs[kb + 1][ldr] = vx.y;
            xs[kb + 2][ldr] = vx.z; xs[kb + 3][ldr] = vx.w;
            ys[kb + 0][ldr] = vy.x; ys[kb + 1][ldr] = vy.y;
            ys[kb + 2][ldr] = vy.z; ys[kb + 3][ldr] = vy.w;
        }
        __syncthreads();
        #pragma unroll 4
        for (int kk = 0; kk < 32; ++kk) {
            float4 a0 = *(const float4*)&xs[kk][8 * ty];
            float4 a1 = *(const float4*)&xs[kk][8 * ty + 4];
            float4 b0 = *(const float4*)&ys[kk][8 * tx];
            float4 b1 = *(const float4*)&ys[kk][8 * tx + 4];
            float av[8] = {a0.x, a0.y, a0.z, a0.w, a1.x, a1.y, a1.z, a1.w};
            float bv[8] = {b0.x, b0.y, b0.z, b0.w, b1.x, b1.y, b1.z, b1.w};
            #pragma unroll
            for (int di = 0; di < 8; ++di)
                #pragma unroll
                for (int dj = 0; dj < 8; ++dj)
                    acc[di][dj] = fmaf(av[di], bv[dj], acc[di][dj]);
        }
        __syncthreads();
    }

    float xqv[8], yqv[8], srow[8];
    #pragma unroll
    for (int di = 0; di < 8; ++di) { xqv[di] = xsq[i0 + 8 * ty + di]; srow[di] = 0.f; }
    #pragma unroll
    for (int dj = 0; dj < 8; ++dj) yqv[dj] = ysq[j0 + 8 * tx + dj];

    #pragma unroll
    for (int di = 0; di < 8; ++di) {
        const int i = i0 + 8 * ty + di;
        #pragma unroll
        for (int dj = 0; dj < 8; ++dj) {
            const int j = j0 + 8 * tx + dj;
            float d2 = fmaxf(xqv[di] + yqv[dj] - 2.0f * acc[di][dj], 0.0f);
            if (i != j) {
                float w = __expf(-0.5f * d2);
                srow[di] += w;
                if (d2 < CUTOFF_F) {
                    const float* Yrow = Y + (size_t)j * 128;
                    for (int k = 0; k < 128; ++k)
                        atomicAdd(&accT[(size_t)i * 128 + k], w * Yrow[k]);
                }
            }
        }
    }
    #pragma unroll
    for (int di = 0; di < 8; ++di) {
        float v = srow[di];
        #pragma unroll
        for (int off = 8; off > 0; off >>= 1) v += __shfl_down(v, off, 16);
        if (tx == 0) atomicAdd(&S[i0 + 8 * ty + di], v);
    }
}

__global__ __launch_bounds__(256) void finalize_k(
    const float* __restrict__ x, const float* __restrict__ ws,
    float* __restrict__ out)
{
    const uint gid = blockIdx.x * 256u + threadIdx.x;  // 0..524287
    const uint i = gid >> 7;
    const float spv = ws[i], snv = ws[4096 + i];
    const float denp = fmaxf(spv, EPSV), denn = fmaxf(snv, EPSV);
    const float c = 0.5f * snv / denn - spv / denp;
    out[gid] = x[gid] * c
             + ws[ACC_IDX + gid] / denp
             - 0.5f * ws[ACC_IDX + 524288u + gid] / denn;
}

extern "C" void kernel_launch(void* const* d_in, const int* in_sizes, int n_in,
                              void* d_out, int out_size, void* d_ws, size_t ws_size,
                              hipStream_t stream)
{
    const float* x  = (const float*)d_in[0];
    const float* yp = (const float*)d_in[1];
    const float* yn = (const float*)d_in[2];
    float* out = (float*)d_out;
    float* ws  = (float*)d_ws;

    const bool use_mfma = (ws_size >= WS_NEED);

    prep_lite<<<3072, 256, 0, stream>>>(x, yp, yn, ws);
    dim3 ga(32, 32, 2);
    if (use_mfma) {
        phase_a_mfma<<<ga, 256, 0, stream>>>(x, yp, yn, ws);
    } else {
        phase_a_f32<<<ga, 256, 0, stream>>>(x, yp, yn, ws);
    }
    finalize_k<<<2048, 256, 0, stream>>>(x, ws, out);
}

// Round 13
// 100.789 us; speedup vs baseline: 1.0247x; 1.0081x over previous
//
#include <hip/hip_runtime.h>
#include <math.h>

// B=4096 rows, D=128 fp32.
// v = x*(-sp/denp + 0.5*sn/denn) + (Wp@yp)/denp - 0.5*(Wn@yn)/denn
// s ~ 1e-26 << EPS=1e-8; only pairs with d2 < ~146 matter (threshold 2e-20).
// Round 13: r12 + cheap swizzled-bf16 matrix build in prep (direct permuted
// stores, no LDS/barrier) + r11's global_load_lds phase_a staging from the
// warm 1MB/matrix bf16 images. Rationale: phase_a's pin at ~41us == 268MB
// logical staging (fp32, 32x tile re-reads, >L2 working set) / ~6.5TB/s L3;
// bf16 matrices halve it (r5/r11 both broke <40us; r11 lost the gain to an
// expensive LDS-based prep build). Flush: exact fp32 dot per survivor,
// unscaled w*y[j] acc atomics; finalize applies exact 1/den. No global
// counters (r2-r4: shared-address atomic chains cost 40-120us).

#define EPSV 1e-8f
#define CUTOFF_F 162.0f
#define LCAP 512

typedef unsigned int uint;
typedef unsigned short ushort;
typedef __attribute__((ext_vector_type(8))) short bf16x8;
typedef __attribute__((ext_vector_type(4))) float f32x4;

// ws float layout: 0 sp[4096]; 4096 sn[4096]; 8192 xsq[4096];
//   12288 ysqp[4096]; 16384 ysqn[4096];
//   20480 accp[524288]; 544768 accn[524288]  (ends float 1069056 = 4.28 MB)
// bytes: 4718592 XA bf16[4096*128]; +1MiB YPB; +2MiB YNB (end 7864320)
#define ACC_IDX 20480u
#define XA_BYTE 4718592u
#define MAT_BYTES 1048576u
#define WS_NEED 7864320u

static __device__ __forceinline__ ushort bf16_rne(float v) {
    uint u = __float_as_uint(v);
    uint r = (u + 0x7FFFu + ((u >> 16) & 1u)) >> 16;
    return (ushort)r;
}

typedef const __attribute__((address_space(1))) uint guint;
typedef __attribute__((address_space(3))) uint luint;
static __device__ __forceinline__ void lds_load16(const void* g, void* l) {
    __builtin_amdgcn_global_load_lds((guint*)g, (luint*)l, 16, 0, 0);
}

// norms + swizzled bf16 matrix build (direct permuted stores) + zeroing.
// Swizzle: within each 64-elem K-group, physical chunk c (8 bf16) holds
// logical chunk c ^ (row&7). Lane l holds elements 2l,2l+1 = logical chunk
// (l>>2)&7 of group l>>5, word l&3 -> one store, same 256B segment.
__global__ __launch_bounds__(256) void prep_k(
    const float* __restrict__ x, const float* __restrict__ yp,
    const float* __restrict__ yn, float* __restrict__ ws,
    unsigned char* __restrict__ wsb, int build)
{
    const int t = threadIdx.x, wv = t >> 6, lane = t & 63;
    const int rid = blockIdx.x * 4 + wv;          // 0..12287
    const int seg = rid >> 12;                    // 0:x 1:yp 2:yn
    const int row = rid & 4095;
    const float* src = (seg == 0) ? x : (seg == 1) ? yp : yn;

    float2 v = ((const float2*)(src + (size_t)row * 128))[lane];
    float ss = v.x * v.x + v.y * v.y;
    #pragma unroll
    for (int off = 32; off > 0; off >>= 1) ss += __shfl_down(ss, off);
    if (lane == 0) ws[8192 + seg * 4096 + row] = ss;

    if (build) {
        const uint packed = (uint)bf16_rne(v.x) | ((uint)bf16_rne(v.y) << 16);
        const int g = lane >> 5;                  // 64-elem group 0..1
        const int c = (lane >> 2) & 7;            // logical chunk in group
        const int pw = g * 32 + (((c ^ (row & 7)) << 2) | (lane & 3));
        uint* dst = (uint*)(wsb + XA_BYTE + (size_t)seg * MAT_BYTES) + (size_t)row * 64;
        dst[pw] = packed;
    }

    const uint gid = blockIdx.x * 256u + (uint)t; // 0..786431
    if (gid < 8192u) ws[gid] = 0.0f;              // sp, sn
    if (gid < 262144u)                            // acc: 1048576 floats as float4
        ((f32x4*)(ws + ACC_IDX))[gid] = (f32x4)0.0f;
}

// MFMA filter GEMM, one field per block-z. 128x128 tile, 4 waves x 64x64.
// global_load_lds staging from the warm bf16 matrices; K=128 in 2 rounds.
__global__ __launch_bounds__(256) void phase_a_mfma(
    const float* __restrict__ x, const float* __restrict__ yp,
    const float* __restrict__ yn,
    const unsigned char* __restrict__ wsb, float* __restrict__ wsf)
{
    const int f = blockIdx.z;
    const ushort* __restrict__ XA = (const ushort*)(wsb + XA_BYTE);
    const ushort* __restrict__ YB = (const ushort*)(wsb + XA_BYTE + (f ? 2u : 1u) * MAT_BYTES);
    const float* __restrict__ Yg  = f ? yn : yp;

    __shared__ ushort As[128 * 64];   // 16 KB per K-half, [8-row grp][64]
    __shared__ ushort Bs[128 * 64];
    __shared__ uint pbuf[LCAP];       // 2 KB pair keys
    __shared__ uint pcnt;

    const int t = threadIdx.x;
    const int lane = t & 63, wv = t >> 6;
    const int wr = wv >> 1, wc = wv & 1;          // 64x64 per wave
    const int i0 = blockIdx.y * 128, j0 = blockIdx.x * 128;
    const int m = lane & 15, qd = lane >> 4;
    const int srow = lane >> 3;                   // 0..7
    const int scol = lane & 7;                    // physical chunk 0..7

    if (t == 0) pcnt = 0;

    f32x4 acc[4][4];
    #pragma unroll
    for (int a = 0; a < 4; ++a)
        #pragma unroll
        for (int bb = 0; bb < 4; ++bb) acc[a][bb] = (f32x4)0.0f;

    for (int k0 = 0; k0 < 128; k0 += 64) {
        #pragma unroll
        for (int q = 0; q < 4; ++q) {
            const int grp = 4 * wv + q;           // 0..15 (8 rows each)
            const int r = grp * 8 + srow;
            lds_load16(XA + (size_t)(i0 + r) * 128 + k0 + scol * 8, &As[grp * 512]);
            lds_load16(YB + (size_t)(j0 + r) * 128 + k0 + scol * 8, &Bs[grp * 512]);
        }
        __syncthreads();
        #pragma unroll
        for (int ks = 0; ks < 2; ++ks) {
            const int ca = (4 * ks + qd) ^ (m & 7);   // ra&7 == m&7
            bf16x8 av[4], bv[4];
            #pragma unroll
            for (int ff = 0; ff < 4; ++ff) {
                const int ra = 64 * wr + 16 * ff + m;
                av[ff] = *(const bf16x8*)&As[ra * 64 + ca * 8];
                const int rb = 64 * wc + 16 * ff + m;
                bv[ff] = *(const bf16x8*)&Bs[rb * 64 + ca * 8];
            }
            #pragma unroll
            for (int fi = 0; fi < 4; ++fi)
                #pragma unroll
                for (int fj = 0; fj < 4; ++fj)
                    acc[fi][fj] = __builtin_amdgcn_mfma_f32_16x16x32_bf16(
                        av[fi], bv[fj], acc[fi][fj], 0, 0, 0);
        }
        __syncthreads();
    }

    // epilogue: approximate d2 filter (C layout: col=lane&15, row=qd*4+rg)
    const float* __restrict__ xsq = wsf + 8192;
    const float* __restrict__ ysq = wsf + 12288 + f * 4096;
    float xq[4][4], yq[4];
    #pragma unroll
    for (int fi = 0; fi < 4; ++fi)
        #pragma unroll
        for (int rg = 0; rg < 4; ++rg)
            xq[fi][rg] = xsq[i0 + 64 * wr + 16 * fi + 4 * qd + rg];
    #pragma unroll
    for (int fj = 0; fj < 4; ++fj)
        yq[fj] = ysq[j0 + 64 * wc + 16 * fj + m];

    #pragma unroll
    for (int fi = 0; fi < 4; ++fi) {
        #pragma unroll
        for (int fj = 0; fj < 4; ++fj) {
            #pragma unroll
            for (int rg = 0; rg < 4; ++rg) {
                const int i = i0 + 64 * wr + 16 * fi + 4 * qd + rg;
                const int j = j0 + 64 * wc + 16 * fj + m;
                float d2a = xq[fi][rg] + yq[fj] - 2.0f * acc[fi][fj][rg];
                if (d2a < CUTOFF_F && i != j) {
                    uint li = atomicAdd(&pcnt, 1u);   // LDS atomic
                    if (li < LCAP)
                        pbuf[li] = (uint)i | ((uint)j << 12);
                }
            }
        }
    }
    __syncthreads();

    // flush: one wave per pair, exact fp32 dot -> w; unscaled acc atomics
    float* __restrict__ S    = wsf + (f ? 4096 : 0);
    float* __restrict__ accF = wsf + ACC_IDX + (size_t)f * 524288u;
    uint n = pcnt; if (n > LCAP) n = LCAP;
    for (uint p = wv; p < n; p += 4) {
        const uint pk = pbuf[p];
        const uint i = pk & 0xFFFu, j = (pk >> 12) & 0xFFFu;
        float2 xa = ((const float2*)(x + (size_t)i * 128))[lane];
        float2 yb = ((const float2*)(Yg + (size_t)j * 128))[lane];
        float d = xa.x * yb.x + xa.y * yb.y;
        #pragma unroll
        for (int off = 32; off > 0; off >>= 1) d += __shfl_xor(d, off);
        const float d2 = fmaxf(xsq[i] + ysq[j] - 2.0f * d, 0.0f);
        const float w = __expf(-0.5f * d2);
        if (lane == 0) atomicAdd(&S[i], w);           // spread addresses
        float* __restrict__ accT = accF + (size_t)i * 128u;
        atomicAdd(&accT[2 * lane],     w * yb.x);
        atomicAdd(&accT[2 * lane + 1], w * yb.y);
    }
}

// fp32 fallback (only if ws too small — not expected): dense path into the
// same S/acc layout.
__global__ __launch_bounds__(256) void phase_a_f32(
    const float* __restrict__ x, const float* __restrict__ yp,
    const float* __restrict__ yn, float* __restrict__ ws)
{
    const int f = blockIdx.z;
    const float* __restrict__ Y   = f ? yn : yp;
    const float* __restrict__ xsq = ws + 8192;
    const float* __restrict__ ysq = ws + (f ? 16384 : 12288);
    float* __restrict__ S         = ws + (f ? 4096 : 0);
    float* __restrict__ accT      = ws + ACC_IDX + (size_t)f * 524288u;

    __shared__ float xs[32][128 + 4];
    __shared__ float ys[32][128 + 4];

    const int t  = threadIdx.x;
    const int tx = t & 15, ty = t >> 4;
    const int i0 = blockIdx.y * 128, j0 = blockIdx.x * 128;

    float acc[8][8];
    #pragma unroll
    for (int a = 0; a < 8; ++a)
        #pragma unroll
        for (int bb = 0; bb < 8; ++bb) acc[a][bb] = 0.f;

    const int ldr = t >> 1;
    const int ldk = (t & 1) * 16;

    for (int k0 = 0; k0 < 128; k0 += 32) {
        #pragma unroll
        for (int q = 0; q < 4; ++q) {
            float4 vx = *(const float4*)&x[(size_t)(i0 + ldr) * 128 + k0 + ldk + 4 * q];
            float4 vy = *(const float4*)&Y[(size_t)(j0 + ldr) * 128 + k0 + ldk + 4 * q];
            const int kb = ldk + 4 * q;
            xs[kb + 0][ldr] = vx.x; xs[kb + 1][ldr] = vx.y;
            xs[kb + 2][ldr] = vx.z; xs[kb + 3][ldr] = vx.w;
            ys[kb + 0][ldr] = vy.x; ys[kb + 1][ldr] = vy.y;
            ys[kb + 2][ldr] = vy.z; ys[kb + 3][ldr] = vy.w;
        }
        __syncthreads();
        #pragma unroll 4
        for (int kk = 0; kk < 32; ++kk) {
            float4 a0 = *(const float4*)&xs[kk][8 * ty];
            float4 a1 = *(const float4*)&xs[kk][8 * ty + 4];
            float4 b0 = *(const float4*)&ys[kk][8 * tx];
            float4 b1 = *(const float4*)&ys[kk][8 * tx + 4];
            float av[8] = {a0.x, a0.y, a0.z, a0.w, a1.x, a1.y, a1.z, a1.w};
            float bv[8] = {b0.x, b0.y, b0.z, b0.w, b1.x, b1.y, b1.z, b1.w};
            #pragma unroll
            for (int di = 0; di < 8; ++di)
                #pragma unroll
                for (int dj = 0; dj < 8; ++dj)
                    acc[di][dj] = fmaf(av[di], bv[dj], acc[di][dj]);
        }
        __syncthreads();
    }

    float xqv[8], yqv[8], srow[8];
    #pragma unroll
    for (int di = 0; di < 8; ++di) { xqv[di] = xsq[i0 + 8 * ty + di]; srow[di] = 0.f; }
    #pragma unroll
    for (int dj = 0; dj < 8; ++dj) yqv[dj] = ysq[j0 + 8 * tx + dj];

    #pragma unroll
    for (int di = 0; di < 8; ++di) {
        const int i = i0 + 8 * ty + di;
        #pragma unroll
        for (int dj = 0; dj < 8; ++dj) {
            const int j = j0 + 8 * tx + dj;
            float d2 = fmaxf(xqv[di] + yqv[dj] - 2.0f * acc[di][dj], 0.0f);
            if (i != j) {
                float w = __expf(-0.5f * d2);
                srow[di] += w;
                if (d2 < CUTOFF_F) {
                    const float* Yrow = Y + (size_t)j * 128;
                    for (int k = 0; k < 128; ++k)
                        atomicAdd(&accT[(size_t)i * 128 + k], w * Yrow[k]);
                }
            }
        }
    }
    #pragma unroll
    for (int di = 0; di < 8; ++di) {
        float v = srow[di];
        #pragma unroll
        for (int off = 8; off > 0; off >>= 1) v += __shfl_down(v, off, 16);
        if (tx == 0) atomicAdd(&S[i0 + 8 * ty + di], v);
    }
}

__global__ __launch_bounds__(256) void finalize_k(
    const float* __restrict__ x, const float* __restrict__ ws,
    float* __restrict__ out)
{
    const uint gid = blockIdx.x * 256u + threadIdx.x;  // 0..524287
    const uint i = gid >> 7;
    const float spv = ws[i], snv = ws[4096 + i];
    const float denp = fmaxf(spv, EPSV), denn = fmaxf(snv, EPSV);
    const float c = 0.5f * snv / denn - spv / denp;
    out[gid] = x[gid] * c
             + ws[ACC_IDX + gid] / denp
             - 0.5f * ws[ACC_IDX + 524288u + gid] / denn;
}

extern "C" void kernel_launch(void* const* d_in, const int* in_sizes, int n_in,
                              void* d_out, int out_size, void* d_ws, size_t ws_size,
                              hipStream_t stream)
{
    const float* x  = (const float*)d_in[0];
    const float* yp = (const float*)d_in[1];
    const float* yn = (const float*)d_in[2];
    float* out = (float*)d_out;
    float* ws  = (float*)d_ws;
    unsigned char* wsb = (unsigned char*)d_ws;

    const bool use_mfma = (ws_size >= WS_NEED);

    prep_k<<<3072, 256, 0, stream>>>(x, yp, yn, ws, wsb, use_mfma ? 1 : 0);
    dim3 ga(32, 32, 2);
    if (use_mfma) {
        phase_a_mfma<<<ga, 256, 0, stream>>>(x, yp, yn, wsb, ws);
    } else {
        phase_a_f32<<<ga, 256, 0, stream>>>(x, yp, yn, ws);
    }
    finalize_k<<<2048, 256, 0, stream>>>(x, ws, out);
}